// Round 6
// baseline (494.407 us; speedup 1.0000x reference)
//
#include <hip/hip_runtime.h>
#include <stdint.h>

typedef unsigned short u16;
typedef __bf16 bf16x8 __attribute__((ext_vector_type(8)));
typedef float f32x4 __attribute__((ext_vector_type(4)));
typedef unsigned short u16x8 __attribute__((ext_vector_type(8)));
typedef unsigned short u16x4 __attribute__((ext_vector_type(4)));
typedef unsigned short u16x2 __attribute__((ext_vector_type(2)));

#define B_ROWS 4096
#define H_DIM  2048
#define K_DIM  4096   // concat K = IN + H
#define N_DIM  8192   // 4 gates * H (logical; no gates buffer)

__device__ __forceinline__ u16 f2b(float f) {
  union { float f; unsigned int i; } v; v.f = f;
  unsigned int i = v.i;
  return (u16)((i + 0x7fffu + ((i >> 16) & 1u)) >> 16);  // RNE
}
__device__ __forceinline__ float b2f(u16 u) {
  union { unsigned int i; float f; } v; v.i = ((unsigned int)u) << 16; return v.f;
}
__device__ __forceinline__ float sigmoidf_(float x) { return 1.0f / (1.0f + __expf(-x)); }
__device__ __forceinline__ float tanhf_(float x)    { return 1.0f - 2.0f / (__expf(2.0f * x) + 1.0f); }

// async global->LDS, 16B per lane. LDS dest = wave-uniform base + lane*16.
__device__ __forceinline__ void glds16(const u16* g, u16* l) {
  __builtin_amdgcn_global_load_lds(
      (__attribute__((address_space(1))) void*)(g),
      (__attribute__((address_space(3))) void*)(l), 16, 0, 0);
}

// raw LDS byte offset of a generic pointer known to be in LDS
__device__ __forceinline__ uint32_t lds_off(const void* p) {
  return (uint32_t)(uintptr_t)(__attribute__((address_space(3))) const void*)p;
}

// inline-asm ds_read_b128: invisible to the compiler's waitcnt pass (keeps it
// from inserting vmcnt(0) drains against in-flight global_load_lds), and lets
// us use COUNTED lgkmcnt. Every MFMA consumer must be preceded by the matching
// s_waitcnt + sched_barrier(0) — rule #18.
__device__ __forceinline__ bf16x8 ds_read128(uint32_t byte_off) {
  bf16x8 r;
  asm volatile("ds_read_b128 %0, %1" : "=&v"(r) : "v"(byte_off));
  return r;
}
// same, with +4096B immediate (high-half A rows: ra->ra+64 keeps the XOR
// swizzle term (ra>>1)&3 unchanged, so the byte offset is exactly +4096).
__device__ __forceinline__ bf16x8 ds_read128_hi(uint32_t byte_off) {
  bf16x8 r;
  asm volatile("ds_read_b128 %0, %1 offset:4096" : "=&v"(r) : "v"(byte_off));
  return r;
}
#define SCHED_FENCE __builtin_amdgcn_sched_barrier(0)

struct WPtrs { const float* p[8]; };  // w_xi,w_xf,w_xo,w_xc,w_hi,w_hf,w_ho,w_hc (fp32)

// ---------------- prep v2: 128x128 transpose tiles (long spans) ----------------
// Theory: the 64x64 tiles' 256B-read/128B-write spans at 8KB stride are the
// 5x-over-roofline cost. 128x128 doubles both spans, converts to bf16 BEFORE
// LDS (halves LDS bytes; 33.3 KB -> 4 blocks/CU), 16 in-flight loads/thread.
// LDS stride 130 u16 (65 words, odd): phase-1 u16x2 writes hit all 32 banks
// 2-way (free); phase-2 scalar reads ~8-way (380cy/wave << HBM budget).
__global__ __launch_bounds__(256) void prep_all(WPtrs wp,
                                                const float* __restrict__ X,
                                                const float* __restrict__ Hs,
                                                u16* __restrict__ Wt,
                                                u16* __restrict__ Abf) {
  __shared__ u16 lt[128 * 130];
  const int z = blockIdx.z;
  const int tid = threadIdx.x;
  if (z < 8) {
    const int s = z >> 2, g = z & 3;
    const float* __restrict__ w = wp.p[z];
    const int j0 = blockIdx.x * 128, k0 = blockIdx.y * 128;

    // phase 1: read 128 rows x 512B (full-wave 512B spans), cvt, -> LDS
    const int c16 = tid & 31;        // 16B column chunk within 512B row-span
    const int r0 = tid >> 5;         // 0..7
#pragma unroll
    for (int it = 0; it < 16; ++it) {
      const int r = it * 8 + r0;
      float4 v = *(const float4*)(w + (size_t)(k0 + r) * H_DIM + j0 + c16 * 4);
      u16x2 lo, hi;
      lo[0] = f2b(v.x); lo[1] = f2b(v.y);
      hi[0] = f2b(v.z); hi[1] = f2b(v.w);
      *(u16x2*)(lt + r * 130 + c16 * 4)     = lo;
      *(u16x2*)(lt + r * 130 + c16 * 4 + 2) = hi;
    }
    __syncthreads();

    // phase 2: write Wt rows (256B contiguous per row: 16 lanes x 16B)
    const int kc = tid & 15;         // k-octet 0..15 (128 k / 8)
    const int jr0 = tid >> 4;        // 0..15
#pragma unroll
    for (int rr = 0; rr < 8; ++rr) {
      const int jl = rr * 16 + jr0;
      u16x8 v;
#pragma unroll
      for (int i = 0; i < 8; ++i) v[i] = lt[(kc * 8 + i) * 130 + jl];
      const size_t orow = (size_t)(g * H_DIM + j0 + jl);
      *(u16x8*)(Wt + orow * K_DIM + (size_t)(s * H_DIM + k0 + kc * 8)) = v;
    }
  } else {
    // A-convert: fully streaming (proven pattern), re-gridded: 512 blocks,
    // 16 chunks of 8 elems per thread.
    const int cid = (z - 8) * 256 + blockIdx.y * 16 + blockIdx.x;   // 0..511
#pragma unroll
    for (int t = 0; t < 16; ++t) {
      const size_t chunk = (size_t)cid * 4096 + t * 256 + tid;      // 8-elem chunk id
      const int b = (int)(chunk >> 9);
      const int c = ((int)chunk & 511) * 8;
      const float* src = (c < H_DIM) ? (X + (size_t)b * H_DIM + c)
                                     : (Hs + (size_t)b * H_DIM + (c - H_DIM));
      float4 v0 = *(const float4*)(src);
      float4 v1 = *(const float4*)(src + 4);
      u16x8 o;
      o[0] = f2b(v0.x); o[1] = f2b(v0.y); o[2] = f2b(v0.z); o[3] = f2b(v0.w);
      o[4] = f2b(v1.x); o[5] = f2b(v1.y); o[6] = f2b(v1.z); o[7] = f2b(v1.w);
      *(u16x8*)(Abf + chunk * 8) = o;
    }
  }
}

// ---------------- fused GEMM + LSTM epilogue (UNCHANGED from round 5) ----------
#define GLS 260   // gl row-stride in u16: 8B-aligned (260*2%8==0), bank step 2
__global__ __launch_bounds__(512, 2) void gemm_fused(
    const u16* __restrict__ A, const u16* __restrict__ Wt,
    const float* __restrict__ Cin,
    const float* __restrict__ Bi, const float* __restrict__ Bff,
    const float* __restrict__ Bo, const float* __restrict__ Bc,
    float* __restrict__ Out) {
  __shared__ __align__(16) u16 smem[4 * 64 * GLS];
  u16* sA = smem;                 // 4 slots x 16 KB
  u16* sB = smem + 4 * 8192;      // 4 slots x 16 KB
  const int tid = threadIdx.x;
  const int wave = tid >> 6, lane = tid & 63;
  const int wm = wave >> 2, wn = wave & 3;         // 2 x 4 wave grid; gate = wn

  const int wg = (blockIdx.x & 7) * 64 + (blockIdx.x >> 3);
  const int bm = wg & 15;      // 16 M-tiles (4096/256)
  const int bj = wg >> 4;      // 32 j-windows (2048/64)

  const int c0 = wave * 2;
  const int rs0 = c0 * 16 + (lane >> 2);
  const int rs1 = rs0 + 16;
  const int kc0 = (lane & 3) ^ ((rs0 >> 1) & 3);
  const int kc1 = (lane & 3) ^ ((rs1 >> 1) & 3);
  const size_t gA0 = (size_t)(bm * 256 + rs0) * K_DIM + kc0 * 8;
  const size_t gA1 = (size_t)(bm * 256 + rs1) * K_DIM + kc1 * 8;
  const int nB0 = (rs0 >> 6) * 2048 + bj * 64 + (rs0 & 63);
  const int nB1 = (rs1 >> 6) * 2048 + bj * 64 + (rs1 & 63);
  const size_t gB0 = (size_t)nB0 * K_DIM + kc0 * 8;
  const size_t gB1 = (size_t)nB1 * K_DIM + kc1 * 8;

  const int q = lane >> 4;
  uint32_t aOffB[4], bOffB[4];
#pragma unroll
  for (int i = 0; i < 4; ++i) {
    int ra = wm * 128 + i * 16 + (lane & 15);
    aOffB[i] = (uint32_t)(ra * 32 + ((q ^ ((ra >> 1) & 3)) * 8)) * 2u;
  }
#pragma unroll
  for (int i = 0; i < 4; ++i) {
    int rb = wn * 64 + i * 16 + (lane & 15);
    bOffB[i] = (uint32_t)(rb * 32 + ((q ^ ((rb >> 1) & 3)) * 8)) * 2u;
  }
  const uint32_t sAb = lds_off(sA);
  const uint32_t sBb = lds_off(sB);

  f32x4 acc[8][4] = {};
  const int NT = K_DIM / 32;   // 128 K-tiles

  bf16x8 af[4], ag[4], bfE[4], bfO[4];

#pragma unroll
  for (int t = 0; t < 3; ++t) {
    const size_t ko = (size_t)t * 32;
    u16* da = sA + t * 8192;
    u16* db = sB + t * 8192;
    glds16(A  + gA0 + ko, da + c0 * 512);
    glds16(A  + gA1 + ko, da + (c0 + 1) * 512);
    glds16(Wt + gB0 + ko, db + c0 * 512);
    glds16(Wt + gB1 + ko, db + (c0 + 1) * 512);
  }
  asm volatile("s_waitcnt vmcnt(8)" ::: "memory");
  __builtin_amdgcn_s_barrier();
  SCHED_FENCE;
#pragma unroll
  for (int i = 0; i < 4; ++i) af[i]  = ds_read128(sAb + aOffB[i]);
#pragma unroll
  for (int i = 0; i < 4; ++i) bfE[i] = ds_read128(sBb + bOffB[i]);

#define TILE_BODY(T, BFC, BFN)                                                 \
  {                                                                            \
    const int pf = (T) + 3;                                                    \
    const uint32_t aSlot = sAb + (uint32_t)((T) & 3) * 16384u;                 \
    const bool dopf = pf < NT;                                                 \
    const size_t ko = (size_t)pf * 32;                                         \
    if (dopf) {                                                                \
      u16* dA = sA + (pf & 3) * 8192;                                          \
      glds16(A + gA0 + ko, dA + c0 * 512);                                     \
      glds16(A + gA1 + ko, dA + (c0 + 1) * 512);                               \
    }                                                                          \
    _Pragma("unroll")                                                          \
    for (int i = 0; i < 4; ++i) ag[i] = ds_read128_hi(aSlot + aOffB[i]);       \
    asm volatile("s_waitcnt lgkmcnt(4)" ::: "memory");                         \
    SCHED_FENCE;                                                               \
    __builtin_amdgcn_s_setprio(1);                                             \
    _Pragma("unroll")                                                          \
    for (int mi = 0; mi < 4; ++mi)                                             \
      _Pragma("unroll")                                                        \
      for (int ni = 0; ni < 4; ++ni)                                           \
        acc[mi][ni] = __builtin_amdgcn_mfma_f32_16x16x32_bf16(                 \
            af[mi], BFC[ni], acc[mi][ni], 0, 0, 0);                            \
    __builtin_amdgcn_s_setprio(0);                                             \
    if (dopf) {                                                                \
      u16* dB = sB + (pf & 3) * 8192;                                          \
      glds16(Wt + gB0 + ko, dB + c0 * 512);                                    \
      glds16(Wt + gB1 + ko, dB + (c0 + 1) * 512);                              \
    }                                                                          \
    if ((T) < NT - 3)       { asm volatile("s_waitcnt vmcnt(8) lgkmcnt(0)" ::: "memory"); } \
    else if ((T) == NT - 3) { asm volatile("s_waitcnt vmcnt(4) lgkmcnt(0)" ::: "memory"); } \
    else if ((T) == NT - 2) { asm volatile("s_waitcnt vmcnt(0) lgkmcnt(0)" ::: "memory"); } \
    else                    { asm volatile("s_waitcnt lgkmcnt(0)" ::: "memory"); }          \
    if ((T) < NT - 1) __builtin_amdgcn_s_barrier();                            \
    SCHED_FENCE;                                                               \
    if ((T) + 1 < NT) {                                                        \
      const uint32_t aN = sAb + (uint32_t)(((T) + 1) & 3) * 16384u;            \
      const uint32_t bN = sBb + (uint32_t)(((T) + 1) & 3) * 16384u;            \
      _Pragma("unroll")                                                        \
      for (int i = 0; i < 4; ++i) af[i]  = ds_read128(aN + aOffB[i]);          \
      _Pragma("unroll")                                                        \
      for (int i = 0; i < 4; ++i) BFN[i] = ds_read128(bN + bOffB[i]);          \
    }                                                                          \
    __builtin_amdgcn_s_setprio(1);                                             \
    _Pragma("unroll")                                                          \
    for (int mi = 0; mi < 4; ++mi)                                             \
      _Pragma("unroll")                                                        \
      for (int ni = 0; ni < 4; ++ni)                                           \
        acc[4 + mi][ni] = __builtin_amdgcn_mfma_f32_16x16x32_bf16(             \
            ag[mi], BFC[ni], acc[4 + mi][ni], 0, 0, 0);                        \
    __builtin_amdgcn_s_setprio(0);                                             \
  }

  for (int T2 = 0; T2 < NT; T2 += 2) {
    TILE_BODY(T2,     bfE, bfO);
    TILE_BODY(T2 + 1, bfO, bfE);
  }
#undef TILE_BODY

  // epilogue phase 1: acc -> bf16 -> gl[gate][j][row] (aliases sA/sB)
  __syncthreads();
  u16* gl = smem;
  {
    const int rowb = wm * 128 + (lane >> 4) * 4;
    const int jb   = lane & 15;
#pragma unroll
    for (int mi = 0; mi < 8; ++mi) {
#pragma unroll
      for (int ni = 0; ni < 4; ++ni) {
        const int row = rowb + mi * 16;
        const int j = jb + ni * 16;
        u16x4 o;
#pragma unroll
        for (int r = 0; r < 4; ++r) o[r] = f2b(acc[mi][ni][r]);
        *(u16x4*)(gl + (size_t)(wn * 64 + j) * GLS + row) = o;
      }
    }
  }
  __syncthreads();

  // epilogue phase 2: LSTM nonlinearity
  {
    const int j = tid & 63;
    const int rg = tid >> 6;
    const int jg = bj * 64 + j;
    const float bi = Bi[jg], bf_ = Bff[jg], bo = Bo[jg], bc = Bc[jg];
    const size_t CH = (size_t)B_ROWS * H_DIM;
#pragma unroll
    for (int it = 0; it < 8; ++it) {
      const int row = rg * 4 + it * 32;
      u16x4 iv = *(const u16x4*)(gl + (size_t)(0 * 64 + j) * GLS + row);
      u16x4 fv = *(const u16x4*)(gl + (size_t)(1 * 64 + j) * GLS + row);
      u16x4 ov = *(const u16x4*)(gl + (size_t)(2 * 64 + j) * GLS + row);
      u16x4 gv = *(const u16x4*)(gl + (size_t)(3 * 64 + j) * GLS + row);
      const size_t grow = (size_t)(bm * 256 + row);
#pragma unroll
      for (int k = 0; k < 4; ++k) {
        const size_t gidx = (grow + k) * H_DIM + jg;
        float cold = Cin[gidx];
        float it_ = sigmoidf_(b2f(iv[k]) + bi);
        float ft_ = sigmoidf_(b2f(fv[k]) + bf_);
        float ot_ = sigmoidf_(b2f(ov[k]) + bo);
        float gt_ = tanhf_(b2f(gv[k]) + bc);
        float ct  = cold * ft_ + it_ * gt_;
        Out[gidx]      = ot_ * tanhf_(ct);   // h_t
        Out[CH + gidx] = ct;                 // c_t
      }
    }
  }
}

extern "C" void kernel_launch(void* const* d_in, const int* in_sizes, int n_in,
                              void* d_out, int out_size, void* d_ws, size_t ws_size,
                              hipStream_t stream) {
  const float* X   = (const float*)d_in[0];
  const float* Hs  = (const float*)d_in[1];
  const float* Cin = (const float*)d_in[2];
  WPtrs wp;
  for (int i = 0; i < 8; ++i) wp.p[i] = (const float*)d_in[3 + i];
  const float* Bi = (const float*)d_in[11];
  const float* Bf = (const float*)d_in[12];
  const float* Bo = (const float*)d_in[13];
  const float* Bc = (const float*)d_in[14];

  u16* Wt    = (u16*)d_ws;                        // [8192][4096] bf16 = 67.1 MB
  u16* Abf   = Wt + (size_t)N_DIM * K_DIM;        // [4096][4096] bf16 = 33.6 MB
  float* Out = (float*)d_out;

  prep_all<<<dim3(16, 16, 10), 256, 0, stream>>>(wp, X, Hs, Wt, Abf);
  gemm_fused<<<16 * 32, 512, 0, stream>>>(Abf, Wt, Cin, Bi, Bf, Bo, Bc, Out);
}